// Round 1
// baseline (168.102 us; speedup 1.0000x reference)
//
#include <hip/hip_runtime.h>
#include <math.h>

#define T_STEPS 200
#define BB 512
#define DD 32
#define LMBD 1.0f

// ws layout (in floats)
#define WS_MINV 0        // sigma^{-T} row-major [i][k], 1024
#define WS_A    1024     // A = sigma sigma^T row-major, 1024
#define WS_W    2048     // weight[512]
#define WS_PART 2560     // per-b partial sums [512]
#define WS_C    3072     // c buffer [200][512][32]

// ---------------------------------------------------------------------------
// Kernel 1: sigma inverse (Gauss-Jordan w/ partial pivoting), A = sigma*sigma^T,
// weight = exp(log_pd + log_ps + log_tw)
// ---------------------------------------------------------------------------
__global__ __launch_bounds__(512) void prep_kernel(
    const float* __restrict__ sigma,
    const float* __restrict__ lpd, const float* __restrict__ lps,
    const float* __restrict__ ltw,
    float* __restrict__ ws)
{
    __shared__ float aug[32][68];   // [sigma | I]
    __shared__ float sg[32][33];    // original sigma copy
    __shared__ float farr[32];
    __shared__ float pinv_s;
    __shared__ int   piv_idx;
    const int tid = threadIdx.x;

    // weight
    if (tid < 512) ws[WS_W + tid] = expf(lpd[tid] + lps[tid] + ltw[tid]);

    for (int idx = tid; idx < 1024; idx += 512) {
        int r = idx >> 5, c = idx & 31;
        float v = sigma[idx];
        sg[r][c] = v;
        aug[r][c] = v;
        aug[r][32 + c] = (r == c) ? 1.0f : 0.0f;
    }
    __syncthreads();

    for (int k = 0; k < 32; ++k) {
        // partial-pivot argmax over rows >= k (lanes 0..31 of wave 0)
        if (tid < 32) {
            float val = -1.0f; int idx = k;
            if (tid >= k) { val = fabsf(aug[tid][k]); idx = tid; }
            #pragma unroll
            for (int m = 1; m < 32; m <<= 1) {
                float ov = __shfl_xor(val, m);
                int   oi = __shfl_xor(idx, m);
                if (ov > val) { val = ov; idx = oi; }
            }
            if (tid == 0) piv_idx = idx;
        }
        __syncthreads();
        const int p = piv_idx;
        if (tid < 64) {   // swap rows k and p (self-swap safe)
            float tmp = aug[k][tid];
            aug[k][tid] = aug[p][tid];
            aug[p][tid] = tmp;
        }
        __syncthreads();
        if (tid == 0) pinv_s = 1.0f / aug[k][k];
        __syncthreads();
        if (tid < 64) aug[k][tid] *= pinv_s;
        __syncthreads();
        if (tid < 32) farr[tid] = aug[tid][k];
        __syncthreads();
        for (int idx = tid; idx < 2048; idx += 512) {
            int r = idx >> 6, c = idx & 63;
            if (r != k) aug[r][c] -= farr[r] * aug[k][c];
        }
        __syncthreads();
    }

    // Minv[i][k] = sigma^{-T}[i,k] = inv[k][i] = aug[k][32+i]
    for (int idx = tid; idx < 1024; idx += 512) {
        int i = idx >> 5, k2 = idx & 31;
        ws[WS_MINV + idx] = aug[k2][32 + i];
    }
    // A[i][j] = sum_k sigma[i,k]*sigma[j,k]
    for (int idx = tid; idx < 1024; idx += 512) {
        int i = idx >> 5, j = idx & 31;
        float s = 0.0f;
        #pragma unroll
        for (int k2 = 0; k2 < 32; ++k2) s += sg[i][k2] * sg[j][k2];
        ws[WS_A + idx] = s;
    }
}

// ---------------------------------------------------------------------------
// Kernel 2: c[t,b,i] = dt*nabla_f[t,b,i] + sum_j nabla_b[t,b,i,j] * v[t,b,j]
// where v = sigma^{-T} * ( -sqrt(LMBD*dt)*noise - dt*control )
// One workgroup = one t x 8 b's, 256 threads = (bl, i).
// ---------------------------------------------------------------------------
__global__ __launch_bounds__(256) void c_kernel(
    const float* __restrict__ ts,
    const float* __restrict__ noises,
    const float* __restrict__ controls,
    const float* __restrict__ nabla_f,
    const float* __restrict__ nabla_b,
    float* __restrict__ ws)
{
    __shared__ float w8[8 * 36];
    __shared__ float v8[8 * 36];

    const int t   = blockIdx.x;
    const int b0  = blockIdx.y << 3;   // 8 b's per block
    const int tid = threadIdx.x;
    const int bl  = tid >> 5;
    const int i   = tid & 31;

    const float dt  = ts[t + 1] - ts[t];
    const float sdt = sqrtf(LMBD * dt);

    // per-thread row i of sigma^{-T} (L1-hot, 32 VGPRs)
    float4 mrow[8];
    {
        const float4* mp = (const float4*)(ws + WS_MINV + i * 32);
        #pragma unroll
        for (int c = 0; c < 8; ++c) mrow[c] = mp[c];
    }

    const int base = (t * BB + b0) * DD;   // flat (t,b0,0); fits in int

    // combined vector w = -sqrt(lmbd*dt)*n - dt*ctl  (256 contiguous elements)
    {
        float nv = noises[base + tid];
        float cv = controls[base + tid];
        w8[bl * 36 + i] = -sdt * nv - dt * cv;
    }
    __syncthreads();

    // v_i = <Minv row i, w[bl]>
    float v = 0.0f;
    {
        const float4* wr = (const float4*)(w8 + bl * 36);
        #pragma unroll
        for (int c = 0; c < 8; ++c) {
            float4 a = wr[c];
            v += mrow[c].x * a.x + mrow[c].y * a.y + mrow[c].z * a.z + mrow[c].w * a.w;
        }
    }
    v8[bl * 36 + i] = v;
    __syncthreads();

    // p = <nabla_b[t,b,i,:], v[bl]>
    float p = 0.0f;
    {
        const float4* br = (const float4*)(nabla_b + ((size_t)(base + tid) << 5));
        const float4* vr = (const float4*)(v8 + bl * 36);
        #pragma unroll
        for (int c = 0; c < 8; ++c) {
            float4 bb = br[c];
            float4 vv = vr[c];
            p += bb.x * vv.x + bb.y * vv.y + bb.z * vv.z + bb.w * vv.w;
        }
    }
    float cval = dt * nabla_f[base + tid] + p;
    ws[WS_C + base + tid] = cval;
}

// ---------------------------------------------------------------------------
// Kernel 3: per-b suffix scan + E = sum_t e e^T + contraction with A.
// One workgroup per b, 256 threads.
// ---------------------------------------------------------------------------
__global__ __launch_bounds__(256) void loss_kernel(
    const float* __restrict__ nabla_V,
    const float* __restrict__ nabla_g,
    float* __restrict__ ws)
{
    __shared__ float s[201 * 36];   // padded stride 36 (16B aligned rows)
    const int b   = blockIdx.x;
    const int tid = threadIdx.x;
    const float* cbuf = ws + WS_C;

    // P0: load c column b; row 200 = nabla_g
    for (int idx = tid; idx < 200 * 32; idx += 256) {
        int t = idx >> 5, i = idx & 31;
        s[t * 36 + i] = cbuf[(t * BB + b) * DD + i];
    }
    if (tid < 32) s[200 * 36 + tid] = nabla_g[b * 32 + tid];
    __syncthreads();

    // P1: suffix scan over t (threads 0..31)
    if (tid < 32) {
        float acc = s[200 * 36 + tid];
        for (int t = 199; t >= 0; --t) {
            acc += s[t * 36 + tid];
            s[t * 36 + tid] = acc;
        }
    }
    __syncthreads();

    // P2: e = S - nabla_V, in place
    for (int idx = tid; idx < 201 * 32; idx += 256) {
        int t = idx >> 5, i = idx & 31;
        s[t * 36 + i] -= nabla_V[(t * BB + b) * DD + i];
    }
    __syncthreads();

    // P3: E[i][jc*4..+3] += e_i * e_j
    const int i  = tid >> 3;
    const int jc = tid & 7;
    float a0 = 0.f, a1 = 0.f, a2 = 0.f, a3 = 0.f;
    for (int t = 0; t <= 200; ++t) {
        float  ei = s[t * 36 + i];
        float4 ej = *(const float4*)&s[t * 36 + jc * 4];
        a0 += ei * ej.x; a1 += ei * ej.y; a2 += ei * ej.z; a3 += ei * ej.w;
    }

    // P4: contract with A, weight, block-reduce
    float4 a4 = *(const float4*)(ws + WS_A + i * 32 + jc * 4);
    float part = a0 * a4.x + a1 * a4.y + a2 * a4.z + a3 * a4.w;
    __syncthreads();            // s is dead; reuse for reduction
    s[tid] = part;
    __syncthreads();
    for (int st = 128; st > 0; st >>= 1) {
        if (tid < st) s[tid] += s[tid + st];
        __syncthreads();
    }
    if (tid == 0) ws[WS_PART + b] = ws[WS_W + b] * s[0];
}

// ---------------------------------------------------------------------------
// Kernel 4: deterministic final reduction
// ---------------------------------------------------------------------------
__global__ __launch_bounds__(512) void reduce_kernel(
    const float* __restrict__ ws, float* __restrict__ out)
{
    __shared__ float r[512];
    const int tid = threadIdx.x;
    r[tid] = ws[WS_PART + tid];
    __syncthreads();
    for (int st = 256; st > 0; st >>= 1) {
        if (tid < st) r[tid] += r[tid + st];
        __syncthreads();
    }
    if (tid == 0) out[0] = r[0] * (1.0f / (201.0f * 512.0f));
}

extern "C" void kernel_launch(void* const* d_in, const int* in_sizes, int n_in,
                              void* d_out, int out_size, void* d_ws, size_t ws_size,
                              hipStream_t stream) {
    (void)in_sizes; (void)n_in; (void)out_size; (void)ws_size;
    const float* ts       = (const float*)d_in[0];
    // d_in[1] = states: unused (shape only in reference)
    const float* noises   = (const float*)d_in[2];
    const float* controls = (const float*)d_in[3];
    const float* nabla_V  = (const float*)d_in[4];
    const float* nabla_f  = (const float*)d_in[5];
    const float* nabla_b  = (const float*)d_in[6];
    const float* nabla_g  = (const float*)d_in[7];
    const float* sigma    = (const float*)d_in[8];
    const float* lpd      = (const float*)d_in[9];
    const float* lps      = (const float*)d_in[10];
    const float* ltw      = (const float*)d_in[11];
    float* ws  = (float*)d_ws;
    float* out = (float*)d_out;

    prep_kernel<<<1, 512, 0, stream>>>(sigma, lpd, lps, ltw, ws);
    c_kernel<<<dim3(T_STEPS, BB / 8), 256, 0, stream>>>(ts, noises, controls,
                                                        nabla_f, nabla_b, ws);
    loss_kernel<<<BB, 256, 0, stream>>>(nabla_V, nabla_g, ws);
    reduce_kernel<<<1, 512, 0, stream>>>(ws, out);
}

// Round 2
// 152.760 us; speedup vs baseline: 1.1004x; 1.1004x over previous
//
#include <hip/hip_runtime.h>
#include <math.h>

#define T_STEPS 200
#define BB 512
#define DD 32
#define LMBD 1.0f

// ws layout (in floats)
#define WS_MINV 0        // sigma^{-T} row-major [i][k], 1024
#define WS_A    1024     // A = sigma sigma^T row-major, 1024
#define WS_W    2048     // weight[512]
#define WS_PART 2560     // per-b partial sums [512]
#define WS_C    3072     // c buffer [200][512][32]

// ---------------------------------------------------------------------------
// Kernel 1: sigma inverse (Gauss-Jordan w/ partial pivoting), A = sigma*sigma^T,
// weight = exp(log_pd + log_ps + log_tw)
// ---------------------------------------------------------------------------
__global__ __launch_bounds__(512) void prep_kernel(
    const float* __restrict__ sigma,
    const float* __restrict__ lpd, const float* __restrict__ lps,
    const float* __restrict__ ltw,
    float* __restrict__ ws)
{
    __shared__ float aug[32][68];   // [sigma | I]
    __shared__ float sg[32][33];    // original sigma copy
    __shared__ float farr[32];
    __shared__ float pinv_s;
    __shared__ int   piv_idx;
    const int tid = threadIdx.x;

    // weight
    if (tid < 512) ws[WS_W + tid] = expf(lpd[tid] + lps[tid] + ltw[tid]);

    for (int idx = tid; idx < 1024; idx += 512) {
        int r = idx >> 5, c = idx & 31;
        float v = sigma[idx];
        sg[r][c] = v;
        aug[r][c] = v;
        aug[r][32 + c] = (r == c) ? 1.0f : 0.0f;
    }
    __syncthreads();

    for (int k = 0; k < 32; ++k) {
        // partial-pivot argmax over rows >= k (lanes 0..31 of wave 0)
        if (tid < 32) {
            float val = -1.0f; int idx = k;
            if (tid >= k) { val = fabsf(aug[tid][k]); idx = tid; }
            #pragma unroll
            for (int m = 1; m < 32; m <<= 1) {
                float ov = __shfl_xor(val, m);
                int   oi = __shfl_xor(idx, m);
                if (ov > val) { val = ov; idx = oi; }
            }
            if (tid == 0) piv_idx = idx;
        }
        __syncthreads();
        const int p = piv_idx;
        if (tid < 64) {   // swap rows k and p (self-swap safe)
            float tmp = aug[k][tid];
            aug[k][tid] = aug[p][tid];
            aug[p][tid] = tmp;
        }
        __syncthreads();
        if (tid == 0) pinv_s = 1.0f / aug[k][k];
        __syncthreads();
        if (tid < 64) aug[k][tid] *= pinv_s;
        __syncthreads();
        if (tid < 32) farr[tid] = aug[tid][k];
        __syncthreads();
        for (int idx = tid; idx < 2048; idx += 512) {
            int r = idx >> 6, c = idx & 63;
            if (r != k) aug[r][c] -= farr[r] * aug[k][c];
        }
        __syncthreads();
    }

    // Minv[i][k] = sigma^{-T}[i,k] = inv[k][i] = aug[k][32+i]
    for (int idx = tid; idx < 1024; idx += 512) {
        int i = idx >> 5, k2 = idx & 31;
        ws[WS_MINV + idx] = aug[k2][32 + i];
    }
    // A[i][j] = sum_k sigma[i,k]*sigma[j,k]
    for (int idx = tid; idx < 1024; idx += 512) {
        int i = idx >> 5, j = idx & 31;
        float s = 0.0f;
        #pragma unroll
        for (int k2 = 0; k2 < 32; ++k2) s += sg[i][k2] * sg[j][k2];
        ws[WS_A + idx] = s;
    }
}

// ---------------------------------------------------------------------------
// Kernel 2: c[t,b,i] = dt*nabla_f[t,b,i] + sum_j nabla_b[t,b,i,j] * v[t,b,j]
// where v = sigma^{-T} * ( -sqrt(LMBD*dt)*noise - dt*control )
// One workgroup = one t x 8 b's, 256 threads (4 waves).
// Streaming phase: fully coalesced 1KiB/instr loads of nabla_b; each 8-lane
// group owns one row, dot4 + shfl_xor(1,2,4) reduce, shfl-repack so lane l
// holds row l -> one coalesced 64-lane store.
// ---------------------------------------------------------------------------
__global__ __launch_bounds__(256) void c_kernel(
    const float* __restrict__ ts,
    const float* __restrict__ noises,
    const float* __restrict__ controls,
    const float* __restrict__ nabla_f,
    const float* __restrict__ nabla_b,
    float* __restrict__ ws)
{
    __shared__ float w8[8 * 36];
    __shared__ float v8[8 * 36];

    const int t   = blockIdx.x;
    const int b0  = blockIdx.y << 3;   // 8 b's per block
    const int tid = threadIdx.x;
    const int bl  = tid >> 5;          // 0..7 (b-slot for v computation)
    const int i   = tid & 31;

    const float dt  = ts[t + 1] - ts[t];
    const float sdt = sqrtf(LMBD * dt);

    const int base = (t * BB + b0) * DD;   // flat (t,b0,0) vector index

    // combined vector w = -sqrt(lmbd*dt)*n - dt*ctl  (256 contiguous elements)
    {
        float nv = noises[base + tid];
        float cv = controls[base + tid];
        w8[bl * 36 + i] = -sdt * nv - dt * cv;
    }

    // per-thread row i of sigma^{-T} (L2-hot, 32 VGPRs)
    float4 mrow[8];
    {
        const float4* mp = (const float4*)(ws + WS_MINV + i * 32);
        #pragma unroll
        for (int c = 0; c < 8; ++c) mrow[c] = mp[c];
    }
    __syncthreads();

    // v_i = <Minv row i, w[bl]>
    float v = 0.0f;
    {
        const float4* wr = (const float4*)(w8 + bl * 36);
        #pragma unroll
        for (int c = 0; c < 8; ++c) {
            float4 a = wr[c];
            v += mrow[c].x * a.x + mrow[c].y * a.y + mrow[c].z * a.z + mrow[c].w * a.w;
        }
    }
    v8[bl * 36 + i] = v;
    __syncthreads();

    // ---- streaming phase: wave wv owns b-pair (2wv, 2wv+1) = 64 rows = 8KiB
    const int wv = tid >> 6;   // wave id 0..3
    const int l  = tid & 63;   // lane
    const int g  = l & 7;      // column-group within 8-lane row group

    const float4* nb4 = (const float4*)nabla_b + (size_t)(base + (wv << 6)) * 8;

    float myval = 0.0f;
    #pragma unroll
    for (int c = 0; c < 8; ++c) {
        // lane l reads float4 at tile float-offset c*256 + l*4  (coalesced 1KiB)
        float4 nb = nb4[c * 64 + l];
        // this float4 belongs to row r = c*8 + (l>>3), cols g*4..g*4+3,
        // b within pair = c>>2
        const int bloc = (wv << 1) + (c >> 2);
        float4 vv = *(const float4*)&v8[bloc * 36 + (g << 2)];
        float p = nb.x * vv.x + nb.y * vv.y + nb.z * vv.z + nb.w * vv.w;
        // reduce across the 8-lane row group (lanes sharing l>>3)
        p += __shfl_xor(p, 1);
        p += __shfl_xor(p, 2);
        p += __shfl_xor(p, 4);
        // repack: lane l picks up row-group (l&7)'s sum; accept when its row
        // index c*8 + (l&7) == l, i.e. l>>3 == c
        float rc = __shfl(p, (l & 7) << 3);
        myval = ((l >> 3) == c) ? rc : myval;
    }

    // lane l now holds the dot for global row (base + wv*64 + l)
    const int gi = base + (wv << 6) + l;
    ws[WS_C + gi] = dt * nabla_f[gi] + myval;
}

// ---------------------------------------------------------------------------
// Kernel 3: per-b suffix scan + E = sum_t e e^T + contraction with A.
// One workgroup per b, 256 threads.
// ---------------------------------------------------------------------------
__global__ __launch_bounds__(256) void loss_kernel(
    const float* __restrict__ nabla_V,
    const float* __restrict__ nabla_g,
    float* __restrict__ ws)
{
    __shared__ float s[201 * 36];   // padded stride 36 (16B aligned rows)
    const int b   = blockIdx.x;
    const int tid = threadIdx.x;
    const float* cbuf = ws + WS_C;

    // P0: load c column b; row 200 = nabla_g
    for (int idx = tid; idx < 200 * 32; idx += 256) {
        int t = idx >> 5, i = idx & 31;
        s[t * 36 + i] = cbuf[(t * BB + b) * DD + i];
    }
    if (tid < 32) s[200 * 36 + tid] = nabla_g[b * 32 + tid];
    __syncthreads();

    // P1: suffix scan over t (threads 0..31)
    if (tid < 32) {
        float acc = s[200 * 36 + tid];
        for (int t = 199; t >= 0; --t) {
            acc += s[t * 36 + tid];
            s[t * 36 + tid] = acc;
        }
    }
    __syncthreads();

    // P2: e = S - nabla_V, in place
    for (int idx = tid; idx < 201 * 32; idx += 256) {
        int t = idx >> 5, i = idx & 31;
        s[t * 36 + i] -= nabla_V[(t * BB + b) * DD + i];
    }
    __syncthreads();

    // P3: E[i][jc*4..+3] += e_i * e_j
    const int i  = tid >> 3;
    const int jc = tid & 7;
    float a0 = 0.f, a1 = 0.f, a2 = 0.f, a3 = 0.f;
    for (int t = 0; t <= 200; ++t) {
        float  ei = s[t * 36 + i];
        float4 ej = *(const float4*)&s[t * 36 + jc * 4];
        a0 += ei * ej.x; a1 += ei * ej.y; a2 += ei * ej.z; a3 += ei * ej.w;
    }

    // P4: contract with A, weight, block-reduce
    float4 a4 = *(const float4*)(ws + WS_A + i * 32 + jc * 4);
    float part = a0 * a4.x + a1 * a4.y + a2 * a4.z + a3 * a4.w;
    __syncthreads();            // s is dead; reuse for reduction
    s[tid] = part;
    __syncthreads();
    for (int st = 128; st > 0; st >>= 1) {
        if (tid < st) s[tid] += s[tid + st];
        __syncthreads();
    }
    if (tid == 0) ws[WS_PART + b] = ws[WS_W + b] * s[0];
}

// ---------------------------------------------------------------------------
// Kernel 4: deterministic final reduction
// ---------------------------------------------------------------------------
__global__ __launch_bounds__(512) void reduce_kernel(
    const float* __restrict__ ws, float* __restrict__ out)
{
    __shared__ float r[512];
    const int tid = threadIdx.x;
    r[tid] = ws[WS_PART + tid];
    __syncthreads();
    for (int st = 256; st > 0; st >>= 1) {
        if (tid < st) r[tid] += r[tid + st];
        __syncthreads();
    }
    if (tid == 0) out[0] = r[0] * (1.0f / (201.0f * 512.0f));
}

extern "C" void kernel_launch(void* const* d_in, const int* in_sizes, int n_in,
                              void* d_out, int out_size, void* d_ws, size_t ws_size,
                              hipStream_t stream) {
    (void)in_sizes; (void)n_in; (void)out_size; (void)ws_size;
    const float* ts       = (const float*)d_in[0];
    // d_in[1] = states: unused (shape only in reference)
    const float* noises   = (const float*)d_in[2];
    const float* controls = (const float*)d_in[3];
    const float* nabla_V  = (const float*)d_in[4];
    const float* nabla_f  = (const float*)d_in[5];
    const float* nabla_b  = (const float*)d_in[6];
    const float* nabla_g  = (const float*)d_in[7];
    const float* sigma    = (const float*)d_in[8];
    const float* lpd      = (const float*)d_in[9];
    const float* lps      = (const float*)d_in[10];
    const float* ltw      = (const float*)d_in[11];
    float* ws  = (float*)d_ws;
    float* out = (float*)d_out;

    prep_kernel<<<1, 512, 0, stream>>>(sigma, lpd, lps, ltw, ws);
    c_kernel<<<dim3(T_STEPS, BB / 8), 256, 0, stream>>>(ts, noises, controls,
                                                        nabla_f, nabla_b, ws);
    loss_kernel<<<BB, 256, 0, stream>>>(nabla_V, nabla_g, ws);
    reduce_kernel<<<1, 512, 0, stream>>>(ws, out);
}

// Round 3
// 128.024 us; speedup vs baseline: 1.3131x; 1.1932x over previous
//
#include <hip/hip_runtime.h>
#include <math.h>

#define T_STEPS 200
#define BB 512
#define DD 32
#define LMBD 1.0f

// ws layout (in floats)
#define WS_MINV 0        // sigma^{-T} row-major [i][k], 1024
#define WS_A    1024     // A = sigma sigma^T row-major, 1024
#define WS_W    2048     // weight[512]
#define WS_PART 2560     // per-b partial sums [512]
#define WS_C    3072     // c buffer, TRANSPOSED: [b][t][i] = [512][200][32]

// ---------------------------------------------------------------------------
// Kernel 1: prep. weight = exp(lpd+lps+ltw); A = sigma sigma^T (from LDS);
// sigma^{-T} via single-wave register-resident Gauss-Jordan (no pivoting:
// sigma = I + 0.05N is well-conditioned; matches LAPACK inv to ~1e-6).
// Lane j of wave 0 holds column j of [sigma | I]; loop fully unrolled so all
// register indices are compile-time (rule: runtime-indexed arrays -> scratch).
// ---------------------------------------------------------------------------
__global__ __launch_bounds__(512) void prep_kernel(
    const float* __restrict__ sigma,
    const float* __restrict__ lpd, const float* __restrict__ lps,
    const float* __restrict__ ltw,
    float* __restrict__ ws)
{
    __shared__ float sg[32][33];
    const int tid = threadIdx.x;

    ws[WS_W + tid] = expf(lpd[tid] + lps[tid] + ltw[tid]);

    for (int idx = tid; idx < 1024; idx += 512)
        sg[idx >> 5][idx & 31] = sigma[idx];
    __syncthreads();

    // A[i][j] = <sigma row i, sigma row j>  (2 outputs per thread)
    for (int idx = tid; idx < 1024; idx += 512) {
        int i = idx >> 5, j = idx & 31;
        float s = 0.0f;
        #pragma unroll
        for (int k = 0; k < 32; ++k) s += sg[i][k] * sg[j][k];
        ws[WS_A + idx] = s;
    }

    // Gauss-Jordan, wave 0 only, barrier-free
    if (tid < 64) {
        const int l = tid;
        float col[32];
        #pragma unroll
        for (int r = 0; r < 32; ++r) {
            float v = sg[r][l & 31];
            col[r] = (l < 32) ? v : ((r == (l - 32)) ? 1.0f : 0.0f);
        }
        #pragma unroll
        for (int k = 0; k < 32; ++k) {
            float pinv = 1.0f / __shfl(col[k], k);   // a[k][k] from lane k
            col[k] *= pinv;                           // scale row k
            #pragma unroll
            for (int r = 0; r < 32; ++r) {
                if (r == k) continue;
                float f = __shfl(col[r], k);          // a[r][k] (pre-update)
                col[r] -= f * col[k];                 // row r -= f * row k
            }
        }
        // lane 32+c holds sigma^{-1} column c; Minv[i][k] = sigma^{-1}[k][i]
        // => Minv[(l-32)*32 + r] = col[r]   (scatter, 4KB once, L2)
        if (l >= 32) {
            #pragma unroll
            for (int r = 0; r < 32; ++r)
                ws[WS_MINV + (l - 32) * 32 + r] = col[r];
        }
    }
}

// ---------------------------------------------------------------------------
// Kernel 2: c[b][t][i] = dt*nabla_f[t,b,i] + sum_j nabla_b[t,b,i,j] * v[t,b,j]
// v = sigma^{-T} * ( -sqrt(LMBD*dt)*noise - dt*control )
// One workgroup = one t x 8 b's, 256 threads (4 waves). Streaming phase:
// coalesced 1KiB/instr nabla_b loads; 8-lane row groups dot4 + shfl_xor
// reduce + shfl repack; store TRANSPOSED [b][t][i] for loss contiguity.
// ---------------------------------------------------------------------------
__global__ __launch_bounds__(256) void c_kernel(
    const float* __restrict__ ts,
    const float* __restrict__ noises,
    const float* __restrict__ controls,
    const float* __restrict__ nabla_f,
    const float* __restrict__ nabla_b,
    float* __restrict__ ws)
{
    __shared__ float w8[8 * 36];
    __shared__ float v8[8 * 36];

    const int t   = blockIdx.x;
    const int b0  = blockIdx.y << 3;
    const int tid = threadIdx.x;
    const int bl  = tid >> 5;
    const int i   = tid & 31;

    const float dt  = ts[t + 1] - ts[t];
    const float sdt = sqrtf(LMBD * dt);

    const int base = (t * BB + b0) * DD;

    {
        float nv = noises[base + tid];
        float cv = controls[base + tid];
        w8[bl * 36 + i] = -sdt * nv - dt * cv;
    }

    // per-thread row i of sigma^{-T} (L1-hot across blocks)
    float4 mrow[8];
    {
        const float4* mp = (const float4*)(ws + WS_MINV + i * 32);
        #pragma unroll
        for (int c = 0; c < 8; ++c) mrow[c] = mp[c];
    }
    __syncthreads();

    float v = 0.0f;
    {
        const float4* wr = (const float4*)(w8 + bl * 36);
        #pragma unroll
        for (int c = 0; c < 8; ++c) {
            float4 a = wr[c];
            v += mrow[c].x * a.x + mrow[c].y * a.y + mrow[c].z * a.z + mrow[c].w * a.w;
        }
    }
    v8[bl * 36 + i] = v;
    __syncthreads();

    // ---- streaming: wave wv owns b-pair (2wv, 2wv+1) = 64 rows = 8KiB
    const int wv = tid >> 6;
    const int l  = tid & 63;
    const int g  = l & 7;

    const float4* nb4 = (const float4*)nabla_b + (size_t)(base + (wv << 6)) * 8;

    float myval = 0.0f;
    #pragma unroll
    for (int c = 0; c < 8; ++c) {
        float4 nb = nb4[c * 64 + l];                  // coalesced 1KiB
        const int bloc = (wv << 1) + (c >> 2);
        float4 vv = *(const float4*)&v8[bloc * 36 + (g << 2)];
        float p = nb.x * vv.x + nb.y * vv.y + nb.z * vv.z + nb.w * vv.w;
        p += __shfl_xor(p, 1);
        p += __shfl_xor(p, 2);
        p += __shfl_xor(p, 4);
        float rc = __shfl(p, (l & 7) << 3);           // row-group (l&7)'s sum
        myval = ((l >> 3) == c) ? rc : myval;
    }

    // lane l holds dot for row rr = wv*64 + l of the block's 8-b tile
    const int rr    = (wv << 6) + l;
    const int gread = base + rr;                       // [t][b][i] for nabla_f
    const int bloc2 = rr >> 5, i2 = rr & 31;
    ws[WS_C + ((b0 + bloc2) * T_STEPS + t) * DD + i2] =
        dt * nabla_f[gread] + myval;
}

// ---------------------------------------------------------------------------
// Kernel 3: per-b suffix scan (8-way chunked) + E = sum_t e e^T + contraction.
// One workgroup per b, 256 threads. c reads now fully contiguous (25.6KB).
// nabla_V prefetched into registers before the LDS phases to hide latency.
// ---------------------------------------------------------------------------
__global__ __launch_bounds__(256) void loss_kernel(
    const float* __restrict__ nabla_V,
    const float* __restrict__ nabla_g,
    float* __restrict__ ws)
{
    __shared__ float s[201 * 36];
    const int b   = blockIdx.x;
    const int tid = threadIdx.x;

    // prefetch nabla_V (strided 128B rows) into registers, static-indexed
    float vpre[26];
    #pragma unroll
    for (int u = 0; u < 26; ++u) {
        int idx = tid + u * 256;
        if (idx < 201 * 32) {
            int t = idx >> 5, i3 = idx & 31;
            vpre[u] = nabla_V[(t * BB + b) * DD + i3];
        } else vpre[u] = 0.0f;
    }

    // P0: contiguous load of c[b][*][*]; row 200 = nabla_g
    const float* cb = ws + WS_C + b * (T_STEPS * DD);
    for (int idx = tid; idx < T_STEPS * DD; idx += 256)
        s[(idx >> 5) * 36 + (idx & 31)] = cb[idx];
    if (tid < 32) s[200 * 36 + tid] = nabla_g[b * 32 + tid];
    __syncthreads();

    // P1a: local suffix scan within 8 chunks of 25 t's (thread = chunk x i)
    const int cch = tid >> 5, ii = tid & 31;
    {
        float acc = 0.0f;
        for (int k = 24; k >= 0; --k) {
            int a = (cch * 25 + k) * 36 + ii;
            acc += s[a];
            s[a] = acc;
        }
    }
    __syncthreads();

    // P1b: chunk-suffix offsets (chunk head s[25c'] holds chunk total)
    float O = s[200 * 36 + ii];                  // + nabla_g
    for (int c2 = cch + 1; c2 < 8; ++c2) O += s[(c2 * 25) * 36 + ii];
    __syncthreads();

    // P1c: apply offsets
    for (int k = 0; k < 25; ++k) s[(cch * 25 + k) * 36 + ii] += O;
    __syncthreads();

    // P2: e = S - nabla_V (from prefetched registers)
    #pragma unroll
    for (int u = 0; u < 26; ++u) {
        int idx = tid + u * 256;
        if (idx < 201 * 32) s[(idx >> 5) * 36 + (idx & 31)] -= vpre[u];
    }
    __syncthreads();

    // P3: E[i][jc*4..+3] accumulation
    const int i  = tid >> 3;
    const int jc = tid & 7;
    float a0 = 0.f, a1 = 0.f, a2 = 0.f, a3 = 0.f;
    for (int t = 0; t <= 200; ++t) {
        float  ei = s[t * 36 + i];
        float4 ej = *(const float4*)&s[t * 36 + jc * 4];
        a0 += ei * ej.x; a1 += ei * ej.y; a2 += ei * ej.z; a3 += ei * ej.w;
    }

    // P4: contract with A, weight, block-reduce
    float4 a4 = *(const float4*)(ws + WS_A + i * 32 + jc * 4);
    float part = a0 * a4.x + a1 * a4.y + a2 * a4.z + a3 * a4.w;
    __syncthreads();
    s[tid] = part;
    __syncthreads();
    for (int st = 128; st > 0; st >>= 1) {
        if (tid < st) s[tid] += s[tid + st];
        __syncthreads();
    }
    if (tid == 0) ws[WS_PART + b] = ws[WS_W + b] * s[0];
}

// ---------------------------------------------------------------------------
// Kernel 4: deterministic final reduction
// ---------------------------------------------------------------------------
__global__ __launch_bounds__(512) void reduce_kernel(
    const float* __restrict__ ws, float* __restrict__ out)
{
    __shared__ float r[512];
    const int tid = threadIdx.x;
    r[tid] = ws[WS_PART + tid];
    __syncthreads();
    for (int st = 256; st > 0; st >>= 1) {
        if (tid < st) r[tid] += r[tid + st];
        __syncthreads();
    }
    if (tid == 0) out[0] = r[0] * (1.0f / (201.0f * 512.0f));
}

extern "C" void kernel_launch(void* const* d_in, const int* in_sizes, int n_in,
                              void* d_out, int out_size, void* d_ws, size_t ws_size,
                              hipStream_t stream) {
    (void)in_sizes; (void)n_in; (void)out_size; (void)ws_size;
    const float* ts       = (const float*)d_in[0];
    const float* noises   = (const float*)d_in[2];
    const float* controls = (const float*)d_in[3];
    const float* nabla_V  = (const float*)d_in[4];
    const float* nabla_f  = (const float*)d_in[5];
    const float* nabla_b  = (const float*)d_in[6];
    const float* nabla_g  = (const float*)d_in[7];
    const float* sigma    = (const float*)d_in[8];
    const float* lpd      = (const float*)d_in[9];
    const float* lps      = (const float*)d_in[10];
    const float* ltw      = (const float*)d_in[11];
    float* ws  = (float*)d_ws;
    float* out = (float*)d_out;

    prep_kernel<<<1, 512, 0, stream>>>(sigma, lpd, lps, ltw, ws);
    c_kernel<<<dim3(T_STEPS, BB / 8), 256, 0, stream>>>(ts, noises, controls,
                                                        nabla_f, nabla_b, ws);
    loss_kernel<<<BB, 256, 0, stream>>>(nabla_V, nabla_g, ws);
    reduce_kernel<<<1, 512, 0, stream>>>(ws, out);
}

// Round 4
// 111.140 us; speedup vs baseline: 1.5125x; 1.1519x over previous
//
#include <hip/hip_runtime.h>
#include <math.h>

#define T_STEPS 200
#define BB 512
#define DD 32
#define LMBD 1.0f
#define NCH 4          // t-chunks per b
#define CHT 50         // t per chunk

// ws layout (floats)
#define WS_MINV 0                  // sigma^{-T} [i][k], 1024
#define WS_A    1024               // A = sigma sigma^T, 1024
#define WS_W    2048               // weight[512]
#define WS_PART 2560               // per-b partials [512]
#define WS_CT   3072               // chunk c-totals [512][4][32]
#define WS_Y    (3072 + 65536)     // chunk Y [512][4][32]
#define WS_M    (3072 + 131072)    // chunk <A,M> scalars [512][4]

// ---------------------------------------------------------------------------
// Kernel 1: prep. weight = exp(lpd+lps+ltw); A = sigma sigma^T;
// sigma^{-T} via single-wave register Gauss-Jordan (no pivoting; sigma ~ I).
// ---------------------------------------------------------------------------
__global__ __launch_bounds__(512) void prep_kernel(
    const float* __restrict__ sigma,
    const float* __restrict__ lpd, const float* __restrict__ lps,
    const float* __restrict__ ltw,
    float* __restrict__ ws)
{
    __shared__ float sg[32][33];
    const int tid = threadIdx.x;

    ws[WS_W + tid] = expf(lpd[tid] + lps[tid] + ltw[tid]);

    for (int idx = tid; idx < 1024; idx += 512)
        sg[idx >> 5][idx & 31] = sigma[idx];
    __syncthreads();

    for (int idx = tid; idx < 1024; idx += 512) {
        int i = idx >> 5, j = idx & 31;
        float s = 0.0f;
        #pragma unroll
        for (int k = 0; k < 32; ++k) s += sg[i][k] * sg[j][k];
        ws[WS_A + idx] = s;
    }

    if (tid < 64) {
        const int l = tid;
        float col[32];
        #pragma unroll
        for (int r = 0; r < 32; ++r) {
            float v = sg[r][l & 31];
            col[r] = (l < 32) ? v : ((r == (l - 32)) ? 1.0f : 0.0f);
        }
        #pragma unroll
        for (int k = 0; k < 32; ++k) {
            float pinv = 1.0f / __shfl(col[k], k);
            col[k] *= pinv;
            #pragma unroll
            for (int r = 0; r < 32; ++r) {
                if (r == k) continue;
                float f = __shfl(col[r], k);
                col[r] -= f * col[k];
            }
        }
        if (l >= 32) {   // lane 32+c holds sigma^{-1} col c; Minv[i][k]=inv[k][i]
            #pragma unroll
            for (int r = 0; r < 32; ++r)
                ws[WS_MINV + (l - 32) * 32 + r] = col[r];
        }
    }
}

// ---------------------------------------------------------------------------
// Kernel 2 (stream): block = (chunk h, b). Streams nabla_b once; per t:
//   v = Minv * (-sqrt(dt)*n - dt*ctl)       (octet dot + shfl reduce)
//   y(t) = P(t-1) + V(t);  c_t = dt*f + nb.v;  P += c_t
//   Y += y;  M += y y^T   (thread (r,q) holds M[r][4q..4q+3])
// Chunk end: write P (c-total), Y, and <A,M> scalar.
// All compute hides under the coalesced nabla_b stream (1KiB/instr).
// ---------------------------------------------------------------------------
__global__ __launch_bounds__(256) void stream_kernel(
    const float* __restrict__ ts,
    const float* __restrict__ noises,
    const float* __restrict__ controls,
    const float* __restrict__ nabla_f,
    const float* __restrict__ nabla_V,
    const float* __restrict__ nabla_b,
    float* __restrict__ ws)
{
    __shared__ float ts_l[52];
    __shared__ __align__(16) float buf[2][4][32];   // [parity][n,ctl,f,V][i]
    __shared__ __align__(16) float vls[32];
    __shared__ __align__(16) float yls[32];
    __shared__ float red[256];

    const int h   = blockIdx.x;        // 0..3
    const int b   = blockIdx.y;        // 0..511
    const int tid = threadIdx.x;
    const int r   = tid >> 3;          // 0..31 (row / i)
    const int q   = tid & 7;           // 0..7  (4-col group)
    const int w   = tid >> 6;          // wave 0..3
    const int lane = tid & 63;

    const int t0 = h * CHT, t1 = t0 + CHT;

    // per-wave small-array pointer (wave-uniform)
    const float* sp_w = (w == 0) ? noises : (w == 1) ? controls
                       : (w == 2) ? nabla_f : nabla_V;

    // stage ts[t0 .. t0+50]
    if (tid < 51) ts_l[tid] = ts[t0 + tid];
    // stage smalls for t0
    if (lane < 32) buf[0][w][lane] = sp_w[((size_t)t0 * BB + b) * DD + lane];

    // Minv fragment: row r, cols 4q..4q+3 of sigma^{-T}
    float4 Minv4 = *(const float4*)(ws + WS_MINV + r * 32 + 4 * q);
    // first nb tile (4KB, coalesced: lane reads float4 at tid)
    float4 nbCur = ((const float4*)nabla_b + (size_t)(t0 * BB + b) * 256)[tid];

    float P = 0.0f, Yacc = 0.0f;
    float a0 = 0.f, a1 = 0.f, a2 = 0.f, a3 = 0.f;
    __syncthreads();

    for (int t = t0; t < t1; ++t) {
        const int p = t & 1;           // t0 even -> starts at 0
        // --- issue prefetches for t+1 (clamped inside chunk)
        const int tn = (t + 1 < t1) ? t + 1 : t1 - 1;
        float4 nbNext = ((const float4*)nabla_b + (size_t)(tn * BB + b) * 256)[tid];
        float smallNext = 0.0f;
        if (lane < 32) smallNext = sp_w[((size_t)tn * BB + b) * DD + lane];

        const float dt  = ts_l[t - t0 + 1] - ts_l[t - t0];
        const float sdt = sqrtf(LMBD * dt);

        // --- v phase: v_r = sum_k Minv[r][k] * w_k
        {
            float4 n4 = *(const float4*)&buf[p][0][4 * q];
            float4 c4 = *(const float4*)&buf[p][1][4 * q];
            float wx = -sdt * n4.x - dt * c4.x;
            float wy = -sdt * n4.y - dt * c4.y;
            float wz = -sdt * n4.z - dt * c4.z;
            float ww = -sdt * n4.w - dt * c4.w;
            float pv = Minv4.x * wx + Minv4.y * wy + Minv4.z * wz + Minv4.w * ww;
            pv += __shfl_xor(pv, 1);
            pv += __shfl_xor(pv, 2);
            pv += __shfl_xor(pv, 4);
            if (q == 0) vls[r] = pv;
        }
        __syncthreads();

        // --- y, c, P phase
        float yr;
        {
            float Vt = buf[p][3][r];
            yr = P + Vt;                       // uses P(t-1)
            if (q == 0) yls[r] = yr;
            float4 v4 = *(const float4*)&vls[4 * q];
            float pc = nbCur.x * v4.x + nbCur.y * v4.y
                     + nbCur.z * v4.z + nbCur.w * v4.w;
            pc += __shfl_xor(pc, 1);
            pc += __shfl_xor(pc, 2);
            pc += __shfl_xor(pc, 4);
            float fr = buf[p][2][r];
            P += dt * fr + pc;                 // P(t)
            Yacc += yr;
        }
        __syncthreads();

        // --- M accumulate: M[r][4q+k] += y_r * y_{4q+k}
        {
            float4 y4 = *(const float4*)&yls[4 * q];
            a0 += yr * y4.x; a1 += yr * y4.y; a2 += yr * y4.z; a3 += yr * y4.w;
        }
        // stage next smalls into other parity
        if (lane < 32) buf[p ^ 1][w][lane] = smallNext;
        nbCur = nbNext;
        __syncthreads();
    }

    // tail: t = 200 belongs to last chunk: y(200) = P + V(200)
    if (h == NCH - 1) {
        float Vt = nabla_V[((size_t)T_STEPS * BB + b) * DD + r];
        float yr = P + Vt;
        if (q == 0) yls[r] = yr;
        Yacc += yr;
        __syncthreads();
        float4 y4 = *(const float4*)&yls[4 * q];
        a0 += yr * y4.x; a1 += yr * y4.y; a2 += yr * y4.z; a3 += yr * y4.w;
        __syncthreads();
    }

    // chunk epilogue: m = <A, M>, write CT / Y / m
    {
        float4 A4 = *(const float4*)(ws + WS_A + r * 32 + 4 * q);
        float mp = a0 * A4.x + a1 * A4.y + a2 * A4.z + a3 * A4.w;
        red[tid] = mp;
        __syncthreads();
        for (int st = 128; st > 0; st >>= 1) {
            if (tid < st) red[tid] += red[tid + st];
            __syncthreads();
        }
        if (q == 0) {
            ws[WS_CT + (b * NCH + h) * 32 + r] = P;
            ws[WS_Y  + (b * NCH + h) * 32 + r] = Yacc;
        }
        if (tid == 0) ws[WS_M + b * NCH + h] = red[0];
    }
}

// ---------------------------------------------------------------------------
// Kernel 3 (combine): per b, resolve cross-chunk prefix algebra:
//   S = g + sum_h CT_h ; C_h = prefix ; S'_h = S - C_h
//   loss_b = w_b * sum_h [ n_h S'^T A S' - 2 S'^T A Y_h + m_h ]
// ---------------------------------------------------------------------------
__global__ __launch_bounds__(256) void combine_kernel(
    const float* __restrict__ nabla_g,
    float* __restrict__ ws)
{
    __shared__ float ct[NCH][32], Yl[NCH][32];
    __shared__ float Sv[32], Cp[32];
    __shared__ __align__(16) float sp[32];
    __shared__ float red[32];

    const int b   = blockIdx.x;
    const int tid = threadIdx.x;
    const int r   = tid >> 3;
    const int q   = tid & 7;

    if (tid < NCH * 32) {
        int hh = tid >> 5, i = tid & 31;
        ct[hh][i] = ws[WS_CT + (b * NCH + hh) * 32 + i];
        Yl[hh][i] = ws[WS_Y  + (b * NCH + hh) * 32 + i];
    }
    if (tid < 32) Cp[tid] = 0.0f;
    __syncthreads();
    if (tid < 32) {
        float s = nabla_g[b * 32 + tid];
        #pragma unroll
        for (int hh = 0; hh < NCH; ++hh) s += ct[hh][tid];
        Sv[tid] = s;
    }

    float acc = 0.0f;
    float4 A4 = *(const float4*)(ws + WS_A + r * 32 + 4 * q);
    for (int hh = 0; hh < NCH; ++hh) {
        __syncthreads();
        if (tid < 32) sp[tid] = Sv[tid] - Cp[tid];
        __syncthreads();
        float4 s4 = *(const float4*)&sp[4 * q];
        float as = A4.x * s4.x + A4.y * s4.y + A4.z * s4.z + A4.w * s4.w;
        as += __shfl_xor(as, 1);
        as += __shfl_xor(as, 2);
        as += __shfl_xor(as, 4);
        float nh = (hh == NCH - 1) ? (float)(CHT + 1) : (float)CHT;
        if (q == 0) acc += as * (nh * sp[r] - 2.0f * Yl[hh][r]);
        if (tid < 32) Cp[tid] += ct[hh][tid];
    }
    __syncthreads();
    if (q == 0) red[r] = acc;
    __syncthreads();
    if (tid == 0) {
        float s = 0.0f;
        #pragma unroll
        for (int i = 0; i < 32; ++i) s += red[i];
        #pragma unroll
        for (int hh = 0; hh < NCH; ++hh) s += ws[WS_M + b * NCH + hh];
        ws[WS_PART + b] = ws[WS_W + b] * s;
    }
}

// ---------------------------------------------------------------------------
// Kernel 4: deterministic final reduction
// ---------------------------------------------------------------------------
__global__ __launch_bounds__(512) void reduce_kernel(
    const float* __restrict__ ws, float* __restrict__ out)
{
    __shared__ float r[512];
    const int tid = threadIdx.x;
    r[tid] = ws[WS_PART + tid];
    __syncthreads();
    for (int st = 256; st > 0; st >>= 1) {
        if (tid < st) r[tid] += r[tid + st];
        __syncthreads();
    }
    if (tid == 0) out[0] = r[0] * (1.0f / (201.0f * 512.0f));
}

extern "C" void kernel_launch(void* const* d_in, const int* in_sizes, int n_in,
                              void* d_out, int out_size, void* d_ws, size_t ws_size,
                              hipStream_t stream) {
    (void)in_sizes; (void)n_in; (void)out_size; (void)ws_size;
    const float* ts       = (const float*)d_in[0];
    const float* noises   = (const float*)d_in[2];
    const float* controls = (const float*)d_in[3];
    const float* nabla_V  = (const float*)d_in[4];
    const float* nabla_f  = (const float*)d_in[5];
    const float* nabla_b  = (const float*)d_in[6];
    const float* nabla_g  = (const float*)d_in[7];
    const float* sigma    = (const float*)d_in[8];
    const float* lpd      = (const float*)d_in[9];
    const float* lps      = (const float*)d_in[10];
    const float* ltw      = (const float*)d_in[11];
    float* ws  = (float*)d_ws;
    float* out = (float*)d_out;

    prep_kernel<<<1, 512, 0, stream>>>(sigma, lpd, lps, ltw, ws);
    stream_kernel<<<dim3(NCH, BB), 256, 0, stream>>>(ts, noises, controls,
                                                     nabla_f, nabla_V, nabla_b, ws);
    combine_kernel<<<BB, 256, 0, stream>>>(nabla_g, ws);
    reduce_kernel<<<1, 512, 0, stream>>>(ws, out);
}